// Round 1
// baseline (124.456 us; speedup 1.0000x reference)
//
#include <hip/hip_runtime.h>
#include <math.h>

// AtomQueryFieldNet: NQ=4096, NA=512, pair MLP 18->64->64->32->1, cutoff mask,
// per-query 3-vector reduction, 3->64->3 head.
//
// R15: wave-per-query, zero barriers, single dispatch.
//  - 1024 blocks x 256 threads; wave w of block b owns query b*4+w. All blocks
//    resident at t0 (no dispatch tail). No __syncthreads anywhere.
//  - Fused in-wave compaction: 8x64-atom ballot sweep, running popc prefix,
//    scatter into per-wave LDS slice (rbufs[wave]). Same-wave RAW ordered by
//    lgkmcnt (compiler-inserted) -- no barrier needed.
//  - W1 row permute: x'[k] = {rbf[0..15], f0, f1, 1(bias), 0...}. kc=0 frag is
//    pure RBF -> 4 exps/lane/tile (was 8, half were cndmask'd to zero);
//    kc=1 frag is exp-free {f0,f1,1,0}|quad0.
//  - RBF via raw v_exp_f32 (exp2): t = s*(d-c), s=sqrt(10*log2e); arg = -t*t
//    (neg folds into v_mul). Saves the __expf ln2-mul per center.
//  - In-kernel weight gather (128 scalar f32 loads + cvt per wave, L1-hot):
//    repack kernel + d_ws eliminated -> one dispatch per launch.
//  - __launch_bounds__(256,3): cap combined VGPR+AGPR ~170 -> >=3 blocks/CU
//    (R14 was ~2: 64 frag + 32 bias regs on top of 76 arch VGPRs).
//  - MFMA K=16 chaining identity unchanged from R14 (verified layout):
//    B-frag k = quad*4+j == C/D row quad*4+rr, so relu_cvt(c) of layer N is
//    directly the kc=mt B-frag of layer N+1. fp16 in / fp32 accum.

typedef _Float16 f16x4 __attribute__((ext_vector_type(4)));
typedef _Float16 f16x2 __attribute__((ext_vector_type(2)));
typedef float    f32x4 __attribute__((ext_vector_type(4)));

#define CAP 352   // max in-range atoms/query (geometric max ~270)
#define NT  2     // 16-pair tiles per chunk

#define MFMA16(A,B,C) __builtin_amdgcn_mfma_f32_16x16x16f16(A,B,C,0,0,0)

__device__ __forceinline__ float exp2_fast(float x) {
    float r;
    asm("v_exp_f32 %0, %1" : "=v"(r) : "v"(x));
    return r;
}

__device__ __forceinline__ f16x4 relu_cvt(f32x4 c) {
    return f16x4{(_Float16)fmaxf(c[0],0.f), (_Float16)fmaxf(c[1],0.f),
                 (_Float16)fmaxf(c[2],0.f), (_Float16)fmaxf(c[3],0.f)};
}

__global__ __launch_bounds__(256, 3) void aqfn_kernel(
    const float* __restrict__ atom_pos,   // (512,3)
    const float* __restrict__ atom_feat,  // (512,2)
    const float* __restrict__ query_pos,  // (4096,3)
    const float* __restrict__ W1, const float* __restrict__ b1,   // (18,64),(64)
    const float* __restrict__ W2, const float* __restrict__ b2,   // (64,64),(64)
    const float* __restrict__ W3, const float* __restrict__ b3,   // (64,32),(32)
    const float* __restrict__ W4, const float* __restrict__ b4,   // (32,1),(1)
    const float* __restrict__ W5, const float* __restrict__ b5,   // (3,64),(64)
    const float* __restrict__ W6, const float* __restrict__ b6,   // (64,3),(3)
    float* __restrict__ out)              // (4096,3)
{
    __shared__ __align__(16) float4 rbufs[4][CAP];
    __shared__ __align__(8)  f16x2  fbufs[4][CAP];

    const int tid  = threadIdx.x;
    const int wave = __builtin_amdgcn_readfirstlane(tid >> 6);
    const int lane = tid & 63;
    const int col  = lane & 15;
    const int quad = lane >> 4;
    const int q    = blockIdx.x * 4 + wave;   // grid=1024 -> q < 4096 always

    float4* rb = rbufs[wave];
    f16x2*  fb = fbufs[wave];

    // ---- weight gather: f32 -> f16 MFMA A-frags, in-register ----
    // frag elem j of w[kc][mt] = W'[kc*16 + quad*4 + j][mt*16 + col]
    f16x4 w1f[2][4], w2f[4][4], w3f[4][2];
    #pragma unroll
    for (int mt = 0; mt < 4; ++mt) {
        #pragma unroll
        for (int j = 0; j < 4; ++j)   // k 0..15 -> rbf rows = W1 rows 2..17
            w1f[0][mt][j] = (_Float16)W1[(2 + quad*4 + j)*64 + mt*16 + col];
        float e0 = 0.f, e1 = 0.f, e2 = 0.f;
        if (quad == 0) {              // k 16,17,18 -> f0,f1,bias rows
            e0 = W1[      mt*16 + col];
            e1 = W1[ 64 + mt*16 + col];
            e2 = b1[      mt*16 + col];
        }
        w1f[1][mt] = f16x4{(_Float16)e0, (_Float16)e1, (_Float16)e2, (_Float16)0.f};
    }
    #pragma unroll
    for (int kc = 0; kc < 4; ++kc)
        #pragma unroll
        for (int mt = 0; mt < 4; ++mt)
            #pragma unroll
            for (int j = 0; j < 4; ++j)
                w2f[kc][mt][j] = (_Float16)W2[(kc*16 + quad*4 + j)*64 + mt*16 + col];
    #pragma unroll
    for (int kc = 0; kc < 4; ++kc)
        #pragma unroll
        for (int mt = 0; mt < 2; ++mt)
            #pragma unroll
            for (int j = 0; j < 4; ++j)
                w3f[kc][mt][j] = (_Float16)W3[(kc*16 + quad*4 + j)*32 + mt*16 + col];

    float4 b2v[4], b3v[2], w4v[2];
    #pragma unroll
    for (int mt = 0; mt < 4; ++mt) b2v[mt] = *(const float4*)&b2[mt*16 + quad*4];
    #pragma unroll
    for (int mt = 0; mt < 2; ++mt) {
        b3v[mt] = *(const float4*)&b3[mt*16 + quad*4];
        w4v[mt] = *(const float4*)&W4[mt*16 + quad*4];
    }
    const float b4v = b4[0];

    // head weights, hoisted per wave
    const float w5x = W5[lane], w5y = W5[64+lane], w5z = W5[128+lane];
    const float b5v = b5[lane];
    const float w6x = W6[lane*3+0], w6y = W6[lane*3+1], w6z = W6[lane*3+2];

    const float qx = query_pos[q*3+0];
    const float qy = query_pos[q*3+1];
    const float qz = query_pos[q*3+2];

    // ---- fused compaction: ballot + running prefix, no barrier ----
    int off = 0;
    #pragma unroll
    for (int it = 0; it < 8; ++it) {
        const int a = it*64 + lane;
        const float rx = qx - atom_pos[a*3+0];
        const float ry = qy - atom_pos[a*3+1];
        const float rz = qz - atom_pos[a*3+2];
        const float f0 = atom_feat[a*2+0];
        const float f1 = atom_feat[a*2+1];
        const float ex = __fadd_rn(rx, 1e-12f);
        const float ey = __fadd_rn(ry, 1e-12f);
        const float ez = __fadd_rn(rz, 1e-12f);
        const float dd = __fadd_rn(__fadd_rn(__fmul_rn(ex,ex), __fmul_rn(ey,ey)),
                                   __fmul_rn(ez,ez));
        const float dist = sqrtf(dd);
        const unsigned long long m = __ballot(dist <= 6.0f);
        const int p = off + (int)__popcll(m & ((1ull << lane) - 1ull));
        if (((m >> lane) & 1ull) && p < CAP) {
            rb[p] = make_float4(rx, ry, rz, dist);
            fb[p] = f16x2{(_Float16)f0, (_Float16)f1};
        }
        off += (int)__popcll(m);
    }
    const int count = off > CAP ? CAP : off;

    // ---- MLP over this wave's list: 32-pair chunks, all in-register ----
    // centers linspace(0,6,16): c_m = 0.4*m. exp(-10 t^2) = 2^(-(s*t)^2),
    // s = sqrt(10*log2 e) = 3.7982831, step 0.4*s = 1.5193132.
    float wacc0 = 0.f, wacc1 = 0.f, wacc2 = 0.f;
    const int nchunks = (count + (NT*16 - 1)) / (NT*16);
    const float cbase = 1.5193132f * (float)(quad*4);

    #pragma unroll 1
    for (int chunk = 0; chunk < nchunks; ++chunk) {
        const int row0 = chunk * (NT*16);

        float4 rv[NT]; f16x2 ffv[NT];
        #pragma unroll
        for (int u = 0; u < NT; ++u) {
            int pr = row0 + u*16 + col;
            if (pr >= count) pr = count - 1;
            rv[u]  = rb[pr];
            ffv[u] = fb[pr];
        }

        // X B-frags: kc=0 pure RBF (center = quad*4+j), kc=1 = {f0,f1,1,0}|quad0
        f16x4 xa0[NT], xa1[NT];
        #pragma unroll
        for (int u = 0; u < NT; ++u) {
            const float base = __fmul_rn(rv[u].w, 3.7982831f) - cbase;
            #pragma unroll
            for (int j = 0; j < 4; ++j) {
                const float t = base - 1.5193132f * (float)j;
                xa0[u][j] = (_Float16)exp2_fast(t * -t);
            }
            const bool q0 = (quad == 0);
            xa1[u] = f16x4{q0 ? ffv[u][0] : (_Float16)0.f,
                           q0 ? ffv[u][1] : (_Float16)0.f,
                           (_Float16)(q0 ? 1.f : 0.f),
                           (_Float16)0.f};
        }

        // ---- L1: output rows mt*16+quad*4+rr -> next-layer B-frag kc=mt ----
        f16x4 a2[NT][4];
        #pragma unroll
        for (int u = 0; u < NT; ++u)
            #pragma unroll
            for (int mt = 0; mt < 4; ++mt) {
                f32x4 c = {0.f, 0.f, 0.f, 0.f};
                c = MFMA16(w1f[0][mt], xa0[u], c);
                c = MFMA16(w1f[1][mt], xa1[u], c);
                a2[u][mt] = relu_cvt(c);
            }

        // ---- L2 ----
        f16x4 a3[NT][4];
        #pragma unroll
        for (int u = 0; u < NT; ++u)
            #pragma unroll
            for (int mt = 0; mt < 4; ++mt) {
                f32x4 c = {b2v[mt].x, b2v[mt].y, b2v[mt].z, b2v[mt].w};
                #pragma unroll
                for (int kc = 0; kc < 4; ++kc)
                    c = MFMA16(w2f[kc][mt], a2[u][kc], c);
                a3[u][mt] = relu_cvt(c);
            }

        // ---- L3 + L4 partial + quad-reduce + fused accumulation ----
        #pragma unroll
        for (int u = 0; u < NT; ++u) {
            float s = 0.f;
            #pragma unroll
            for (int mt = 0; mt < 2; ++mt) {
                f32x4 c = {b3v[mt].x, b3v[mt].y, b3v[mt].z, b3v[mt].w};
                #pragma unroll
                for (int kc = 0; kc < 4; ++kc)
                    c = MFMA16(w3f[kc][mt], a3[u][kc], c);
                const float* wv = &w4v[mt].x;
                #pragma unroll
                for (int rr = 0; rr < 4; ++rr)
                    s = fmaf(fmaxf(c[rr], 0.f), wv[rr], s);
            }
            s += __shfl_xor(s, 16);   // sum quad partials (rows split over quads)
            s += __shfl_xor(s, 32);
            s += b4v;
            const int   p2  = row0 + u*16 + col;
            const float inv = __builtin_amdgcn_rcpf(rv[u].w + 1e-12f);
            const float wm  = (p2 < count) ? (s * inv) : 0.f;
            wacc0 = fmaf(wm, rv[u].x, wacc0);
            wacc1 = fmaf(wm, rv[u].y, wacc1);
            wacc2 = fmaf(wm, rv[u].z, wacc2);
        }
    }

    // ---- 64-lane butterfly; each pair counted by 4 quads -> x0.25 ----
    #pragma unroll
    for (int o = 1; o < 64; o <<= 1) {
        wacc0 += __shfl_xor(wacc0, o);
        wacc1 += __shfl_xor(wacc1, o);
        wacc2 += __shfl_xor(wacc2, o);
    }
    const float v0 = wacc0 * 0.25f;
    const float v1 = wacc1 * 0.25f;
    const float v2 = wacc2 * 0.25f;

    // ---- head: 3 -> 64 -> 3, per wave (lane = hidden unit) ----
    float th = fmaf(v0, w5x, fmaf(v1, w5y, fmaf(v2, w5z, b5v)));
    th = fmaxf(th, 0.f);
    float o0 = th * w6x, o1 = th * w6y, o2 = th * w6z;
    #pragma unroll
    for (int o = 1; o < 64; o <<= 1) {
        o0 += __shfl_xor(o0, o);
        o1 += __shfl_xor(o1, o);
        o2 += __shfl_xor(o2, o);
    }
    if (lane == 0) {
        out[q*3+0] = o0 + b6[0];
        out[q*3+1] = o1 + b6[1];
        out[q*3+2] = o2 + b6[2];
    }
}

extern "C" void kernel_launch(void* const* d_in, const int* in_sizes, int n_in,
                              void* d_out, int out_size, void* d_ws, size_t ws_size,
                              hipStream_t stream) {
    const float* atom_pos  = (const float*)d_in[0];
    const float* atom_feat = (const float*)d_in[1];
    const float* query_pos = (const float*)d_in[2];
    const float* W1 = (const float*)d_in[3];  const float* b1 = (const float*)d_in[4];
    const float* W2 = (const float*)d_in[5];  const float* b2 = (const float*)d_in[6];
    const float* W3 = (const float*)d_in[7];  const float* b3 = (const float*)d_in[8];
    const float* W4 = (const float*)d_in[9];  const float* b4 = (const float*)d_in[10];
    const float* W5 = (const float*)d_in[11]; const float* b5 = (const float*)d_in[12];
    const float* W6 = (const float*)d_in[13]; const float* b6 = (const float*)d_in[14];
    float* out = (float*)d_out;

    hipLaunchKernelGGL(aqfn_kernel, dim3(1024), dim3(256), 0, stream,
                       atom_pos, atom_feat, query_pos,
                       W1, b1, W2, b2, W3, b3, W4, b4, W5, b5, W6, b6, out);
}

// Round 2
// 113.845 us; speedup vs baseline: 1.0932x; 1.0932x over previous
//
#include <hip/hip_runtime.h>
#include <math.h>

// AtomQueryFieldNet: NQ=4096, NA=512, pair MLP 18->64->64->32->1, cutoff mask,
// per-query 3-vector reduction, 3->64->3 head.
//
// R16: wave-per-query + LDS-resident weights (occupancy fix for R15's spills).
//  - R15 failed: in-kernel scalar weight gather + register-resident frags
//    (96 VGPR) under launch_bounds(256,3) => scratch spills (WRITE_SIZE
//    11.6MB), occupancy 18.8%, dur 50us.
//  - R16: repack kernel restored (frags in d_ws, f16 A-frag layout). Each
//    block stages 16KB of frags into LDS with coalesced 8B loads + ONE
//    __syncthreads. All 4 waves share the copy. Frags re-read per chunk as
//    transient ds_read_b64 (opaque asm offset defeats LICM so they never
//    become 64 resident VGPRs again). Biases stay in regs (32 VGPR).
//  - LDS/block = 4x352x20 (per-wave compaction slices) + 16K weights = 43.5KB
//    -> 3 blocks/CU; combined regs ~130 -> launch_bounds(256,3) holds ->
//    12 waves/CU (was ~6-7).
//  - Keeps R15 wins: wave-per-query (zero block barriers in the MLP path,
//    in-wave ballot-prefix compaction), W1 row permute (kc=0 frag pure RBF,
//    4 exps/tile), raw v_exp_f32 RBF.
//  - MFMA K=16 chaining identity (R14): B-frag k = quad*4+j == C/D row
//    quad*4+rr, so relu_cvt of layer N IS layer N+1's B-frag kc=mt.
//    fp16 in / fp32 accum; absmax ~0.0156.

typedef _Float16 f16x4 __attribute__((ext_vector_type(4)));
typedef _Float16 f16x2 __attribute__((ext_vector_type(2)));
typedef float    f32x4 __attribute__((ext_vector_type(4)));

#define CAP 352   // max in-range atoms/query (geometric max ~270)
#define NT  2     // 16-pair tiles per chunk

#define MFMA16(A,B,C) __builtin_amdgcn_mfma_f32_16x16x16f16(A,B,C,0,0,0)

__device__ __forceinline__ float exp2_fast(float x) {
    float r;
    asm("v_exp_f32 %0, %1" : "=v"(r) : "v"(x));
    return r;
}

__device__ __forceinline__ f16x4 relu_cvt(f32x4 c) {
    return f16x4{(_Float16)fmaxf(c[0],0.f), (_Float16)fmaxf(c[1],0.f),
                 (_Float16)fmaxf(c[2],0.f), (_Float16)fmaxf(c[3],0.f)};
}

// ---- repack: weights -> K=16 MFMA A-fragment order in d_ws ----
// 32 f16x4 frags (8B/lane): f 0..7 L1 (kc*4+mt, kc<2), 8..23 L2 (kc*4+mt,
// kc<4), 24..31 L3 (kc*2+mt, kc<4). elem j: W'[k=kc*16+quad*4+j][mt*16+col].
// W1 is ROW-PERMUTED: k 0..15 = rbf centers (orig rows 2..17), k16=f0(row0),
// k17=f1(row1), k18=b1, k>=19 zero. Biases (float4) at +16KB: 0..3 b2,
// 4..5 b3, 6..7 W4.
__global__ __launch_bounds__(64) void repack_kernel(
    const float* __restrict__ W1, const float* __restrict__ b1,
    const float* __restrict__ W2, const float* __restrict__ b2,
    const float* __restrict__ W3, const float* __restrict__ b3,
    const float* __restrict__ W4, char* __restrict__ ws)
{
    const int b = blockIdx.x, l = threadIdx.x;
    const int col = l & 15, quad = l >> 4;
    if (b < 32) {
        f16x4 v;
        #pragma unroll
        for (int j = 0; j < 4; ++j) {
            float x;
            if (b < 8) {
                const int kc = b >> 2, mt = b & 3;
                const int k = kc*16 + quad*4 + j;
                if (k < 16)       x = W1[(k+2)*64 + mt*16 + col];  // rbf rows
                else if (k == 16) x = W1[        mt*16 + col];     // f0
                else if (k == 17) x = W1[ 64   + mt*16 + col];     // f1
                else if (k == 18) x = b1[        mt*16 + col];     // bias slot
                else              x = 0.0f;
            } else if (b < 24) {
                const int idx = b - 8, kc = idx >> 2, mt = idx & 3;
                const int k = kc*16 + quad*4 + j;
                x = W2[k*64 + mt*16 + col];
            } else {
                const int idx = b - 24, kc = idx >> 1, mt = idx & 1;
                const int k = kc*16 + quad*4 + j;
                x = W3[k*32 + mt*16 + col];
            }
            v[j] = (_Float16)x;
        }
        *(f16x4*)(ws + (b*64 + l)*8) = v;
    } else {
        const int d = b - 32;
        float o[4];
        #pragma unroll
        for (int rr = 0; rr < 4; ++rr) {
            const int idx = quad*4 + rr;
            if (d < 4)      o[rr] = b2[d*16 + idx];
            else if (d < 6) o[rr] = b3[(d-4)*16 + idx];
            else            o[rr] = W4[(d-6)*16 + idx];
        }
        *(float4*)(ws + 16384 + (d*64 + l)*16) = make_float4(o[0],o[1],o[2],o[3]);
    }
}

__global__ __launch_bounds__(256, 3) void aqfn_kernel(
    const float* __restrict__ atom_pos,   // (512,3)
    const float* __restrict__ atom_feat,  // (512,2)
    const float* __restrict__ query_pos,  // (4096,3)
    const float* __restrict__ b4,         // (1)
    const float* __restrict__ W5, const float* __restrict__ b5,  // (3,64),(64)
    const float* __restrict__ W6, const float* __restrict__ b6,  // (64,3),(3)
    const char*  __restrict__ ws,         // repacked weights
    float* __restrict__ out)              // (4096,3)
{
    __shared__ __align__(16) float4 rbufs[4][CAP];  // per-wave compaction slices
    __shared__ __align__(8)  f16x2  fbufs[4][CAP];
    __shared__ __align__(16) f16x4  wlds[2048];     // 32 frags x 64 lanes, 16KB

    const int tid  = threadIdx.x;
    const int wave = __builtin_amdgcn_readfirstlane(tid >> 6);
    const int lane = tid & 63;
    const int col  = lane & 15;
    const int quad = lane >> 4;
    const int q    = blockIdx.x * 4 + wave;   // grid=1024 -> q < 4096 always

    float4* rb = rbufs[wave];
    f16x2*  fb = fbufs[wave];

    // ---- stage weight frags to LDS: 8x coalesced 8B loads per thread ----
    {
        const f16x4* wsrc = (const f16x4*)ws;
        #pragma unroll
        for (int i = 0; i < 8; ++i)
            wlds[tid + i*256] = wsrc[tid + i*256];
    }

    // ---- biases -> regs (32 VGPR), coalesced float4 ----
    const float4* wsb = (const float4*)(ws + 16384);
    float4 b2v[4], b3v[2], w4v[2];
    #pragma unroll
    for (int mt = 0; mt < 4; ++mt) b2v[mt] = wsb[mt*64 + lane];
    #pragma unroll
    for (int mt = 0; mt < 2; ++mt) { b3v[mt] = wsb[(4+mt)*64 + lane];
                                     w4v[mt] = wsb[(6+mt)*64 + lane]; }
    const float b4v = b4[0];

    // head weights, hoisted per wave
    const float w5x = W5[lane], w5y = W5[64+lane], w5z = W5[128+lane];
    const float b5v = b5[lane];
    const float w6x = W6[lane*3+0], w6y = W6[lane*3+1], w6z = W6[lane*3+2];

    const float qx = query_pos[q*3+0];
    const float qy = query_pos[q*3+1];
    const float qz = query_pos[q*3+2];

    // ---- fused compaction: ballot + running prefix, same-wave only ----
    int off = 0;
    #pragma unroll
    for (int it = 0; it < 8; ++it) {
        const int a = it*64 + lane;
        const float rx = qx - atom_pos[a*3+0];
        const float ry = qy - atom_pos[a*3+1];
        const float rz = qz - atom_pos[a*3+2];
        const float f0 = atom_feat[a*2+0];
        const float f1 = atom_feat[a*2+1];
        const float ex = __fadd_rn(rx, 1e-12f);
        const float ey = __fadd_rn(ry, 1e-12f);
        const float ez = __fadd_rn(rz, 1e-12f);
        const float dd = __fadd_rn(__fadd_rn(__fmul_rn(ex,ex), __fmul_rn(ey,ey)),
                                   __fmul_rn(ez,ez));
        const float dist = sqrtf(dd);
        const unsigned long long m = __ballot(dist <= 6.0f);
        const int p = off + (int)__popcll(m & ((1ull << lane) - 1ull));
        if (((m >> lane) & 1ull) && p < CAP) {
            rb[p] = make_float4(rx, ry, rz, dist);
            fb[p] = f16x2{(_Float16)f0, (_Float16)f1};
        }
        off += (int)__popcll(m);
    }
    const int count = off > CAP ? CAP : off;

    // one barrier: wlds visible to all waves (rbuf/fbuf are same-wave)
    __syncthreads();

    // ---- MLP over this wave's list: 32-pair chunks, weights from LDS ----
    // centers linspace(0,6,16): c_m = 0.4*m. exp(-10 t^2) = 2^(-(s*t)^2),
    // s = sqrt(10*log2 e) = 3.7982831, step 0.4*s = 1.5193132.
    float wacc0 = 0.f, wacc1 = 0.f, wacc2 = 0.f;
    const int nchunks = (count + (NT*16 - 1)) / (NT*16);
    const float cbase = 1.5193132f * (float)(quad*4);

    #pragma unroll 1
    for (int chunk = 0; chunk < nchunks; ++chunk) {
        const int row0 = chunk * (NT*16);

        // opaque zero: frag addresses depend on it -> ds_reads can't be
        // hoisted out of the loop into resident VGPRs (that was R14/R15's
        // 64-reg weight footprint).
        int wb = 0;
        asm volatile("" : "+v"(wb));

        float4 rv[NT]; f16x2 ffv[NT];
        #pragma unroll
        for (int u = 0; u < NT; ++u) {
            int pr = row0 + u*16 + col;
            if (pr >= count) pr = count - 1;
            rv[u]  = rb[pr];
            ffv[u] = fb[pr];
        }

        // X B-frags: kc=0 pure RBF (center = quad*4+j), kc=1 = {f0,f1,1,0}|quad0
        f16x4 xa0[NT], xa1[NT];
        #pragma unroll
        for (int u = 0; u < NT; ++u) {
            const float base = __fmul_rn(rv[u].w, 3.7982831f) - cbase;
            #pragma unroll
            for (int j = 0; j < 4; ++j) {
                const float t = base - 1.5193132f * (float)j;
                xa0[u][j] = (_Float16)exp2_fast(t * -t);
            }
            const bool q0 = (quad == 0);
            xa1[u] = f16x4{q0 ? ffv[u][0] : (_Float16)0.f,
                           q0 ? ffv[u][1] : (_Float16)0.f,
                           (_Float16)(q0 ? 1.f : 0.f),
                           (_Float16)0.f};
        }

        // ---- L1: transient frag loads, rows mt*16+quad*4+rr -> B-frag kc=mt
        f16x4 t1[2][4];
        #pragma unroll
        for (int kc = 0; kc < 2; ++kc)
            #pragma unroll
            for (int mt = 0; mt < 4; ++mt)
                t1[kc][mt] = wlds[wb + (kc*4 + mt)*64 + lane];
        f16x4 a2[NT][4];
        #pragma unroll
        for (int u = 0; u < NT; ++u)
            #pragma unroll
            for (int mt = 0; mt < 4; ++mt) {
                f32x4 c = {0.f, 0.f, 0.f, 0.f};
                c = MFMA16(t1[0][mt], xa0[u], c);
                c = MFMA16(t1[1][mt], xa1[u], c);
                a2[u][mt] = relu_cvt(c);
            }

        // ---- L2 ----
        f16x4 t2[4][4];
        #pragma unroll
        for (int kc = 0; kc < 4; ++kc)
            #pragma unroll
            for (int mt = 0; mt < 4; ++mt)
                t2[kc][mt] = wlds[wb + (8 + kc*4 + mt)*64 + lane];
        f16x4 a3[NT][4];
        #pragma unroll
        for (int u = 0; u < NT; ++u)
            #pragma unroll
            for (int mt = 0; mt < 4; ++mt) {
                f32x4 c = {b2v[mt].x, b2v[mt].y, b2v[mt].z, b2v[mt].w};
                #pragma unroll
                for (int kc = 0; kc < 4; ++kc)
                    c = MFMA16(t2[kc][mt], a2[u][kc], c);
                a3[u][mt] = relu_cvt(c);
            }

        // ---- L3 + L4 partial + quad-reduce + fused accumulation ----
        f16x4 t3[4][2];
        #pragma unroll
        for (int kc = 0; kc < 4; ++kc)
            #pragma unroll
            for (int mt = 0; mt < 2; ++mt)
                t3[kc][mt] = wlds[wb + (24 + kc*2 + mt)*64 + lane];
        #pragma unroll
        for (int u = 0; u < NT; ++u) {
            float s = 0.f;
            #pragma unroll
            for (int mt = 0; mt < 2; ++mt) {
                f32x4 c = {b3v[mt].x, b3v[mt].y, b3v[mt].z, b3v[mt].w};
                #pragma unroll
                for (int kc = 0; kc < 4; ++kc)
                    c = MFMA16(t3[kc][mt], a3[u][kc], c);
                const float* wv = &w4v[mt].x;
                #pragma unroll
                for (int rr = 0; rr < 4; ++rr)
                    s = fmaf(fmaxf(c[rr], 0.f), wv[rr], s);
            }
            s += __shfl_xor(s, 16);   // sum quad partials (rows split over quads)
            s += __shfl_xor(s, 32);
            s += b4v;
            const int   p2  = row0 + u*16 + col;
            const float inv = __builtin_amdgcn_rcpf(rv[u].w + 1e-12f);
            const float wm  = (p2 < count) ? (s * inv) : 0.f;
            wacc0 = fmaf(wm, rv[u].x, wacc0);
            wacc1 = fmaf(wm, rv[u].y, wacc1);
            wacc2 = fmaf(wm, rv[u].z, wacc2);
        }
    }

    // ---- 64-lane butterfly; each pair counted by 4 quads -> x0.25 ----
    #pragma unroll
    for (int o = 1; o < 64; o <<= 1) {
        wacc0 += __shfl_xor(wacc0, o);
        wacc1 += __shfl_xor(wacc1, o);
        wacc2 += __shfl_xor(wacc2, o);
    }
    const float v0 = wacc0 * 0.25f;
    const float v1 = wacc1 * 0.25f;
    const float v2 = wacc2 * 0.25f;

    // ---- head: 3 -> 64 -> 3, per wave (lane = hidden unit) ----
    float th = fmaf(v0, w5x, fmaf(v1, w5y, fmaf(v2, w5z, b5v)));
    th = fmaxf(th, 0.f);
    float o0 = th * w6x, o1 = th * w6y, o2 = th * w6z;
    #pragma unroll
    for (int o = 1; o < 64; o <<= 1) {
        o0 += __shfl_xor(o0, o);
        o1 += __shfl_xor(o1, o);
        o2 += __shfl_xor(o2, o);
    }
    if (lane == 0) {
        out[q*3+0] = o0 + b6[0];
        out[q*3+1] = o1 + b6[1];
        out[q*3+2] = o2 + b6[2];
    }
}

extern "C" void kernel_launch(void* const* d_in, const int* in_sizes, int n_in,
                              void* d_out, int out_size, void* d_ws, size_t ws_size,
                              hipStream_t stream) {
    const float* atom_pos  = (const float*)d_in[0];
    const float* atom_feat = (const float*)d_in[1];
    const float* query_pos = (const float*)d_in[2];
    const float* W1 = (const float*)d_in[3];  const float* b1 = (const float*)d_in[4];
    const float* W2 = (const float*)d_in[5];  const float* b2 = (const float*)d_in[6];
    const float* W3 = (const float*)d_in[7];  const float* b3 = (const float*)d_in[8];
    const float* W4 = (const float*)d_in[9];  const float* b4 = (const float*)d_in[10];
    const float* W5 = (const float*)d_in[11]; const float* b5 = (const float*)d_in[12];
    const float* W6 = (const float*)d_in[13]; const float* b6 = (const float*)d_in[14];
    float* out = (float*)d_out;
    char*  ws  = (char*)d_ws;   // 16KB frags + 8KB biases

    hipLaunchKernelGGL(repack_kernel, dim3(40), dim3(64), 0, stream,
                       W1, b1, W2, b2, W3, b3, W4, ws);
    hipLaunchKernelGGL(aqfn_kernel, dim3(1024), dim3(256), 0, stream,
                       atom_pos, atom_feat, query_pos, b4, W5, b5, W6, b6,
                       (const char*)ws, out);
}

// Round 3
// 112.317 us; speedup vs baseline: 1.1081x; 1.0136x over previous
//
#include <hip/hip_runtime.h>
#include <math.h>

// AtomQueryFieldNet: NQ=4096, NA=512, pair MLP 18->64->64->32->1, cutoff mask,
// per-query 3-vector reduction, 3->64->3 head.
//
// R17: 4 blocks/CU, single dispatch round (grid 1024 = 256 CU x 4).
//  - R16 (~35us est): LDS 44.5KB -> 3 blocks/CU -> 768+256 two-round dispatch
//    (2nd round at 1/3 utilization); 32 bias + 7 head resident VGPRs.
//  - fbuf merged into rbuf.w: (f0,f1) as f16x2 BITS in the float4 .w (no FP
//    arithmetic touches it -> bit-exact through LDS). dist recomputed in-loop
//    with the IDENTICAL __fadd_rn/__fmul_rn/sqrtf sequence as pass 1 ->
//    bitwise-same dist, absmax unchanged. Lists 28160 -> 22528 B.
//  - Biases compact in LDS (128 floats, 512B; per-chunk broadcast ds_read_b128
//    behind the opaque offset) instead of 32 resident VGPRs. Head weights
//    (W5/b5/W6) loaded AFTER the loop behind an opaque index: -7 resident.
//  - LDS total 39424 <= 40KB -> 4 blocks/CU; __launch_bounds__(256,4) caps
//    VGPR at 128 (est. peak ~110: t2 32 + a2 16 + a3 16 + b2v 16 + rv 8 +
//    misc). 16 waves/CU (was 12) + no dispatch tail.
//  - Keeps: wave-per-query zero-barrier compaction, W1 row permute (kc=0 frag
//    pure RBF, 4 exps/tile), raw v_exp_f32 RBF, LDS weight frags re-read per
//    chunk (opaque asm offset defeats LICM), K=16 MFMA chaining identity
//    (B-frag k = quad*4+j == C/D row quad*4+rr -> relu_cvt output IS next
//    layer's B-frag). fp16 in / fp32 accum; absmax ~0.0156.

typedef _Float16 f16x4 __attribute__((ext_vector_type(4)));
typedef _Float16 f16x2 __attribute__((ext_vector_type(2)));
typedef float    f32x4 __attribute__((ext_vector_type(4)));

#define CAP 352   // max in-range atoms/query (geometric max ~270, +margin)
#define NT  2     // 16-pair tiles per chunk

#define MFMA16(A,B,C) __builtin_amdgcn_mfma_f32_16x16x16f16(A,B,C,0,0,0)

__device__ __forceinline__ float exp2_fast(float x) {
    float r;
    asm("v_exp_f32 %0, %1" : "=v"(r) : "v"(x));
    return r;
}

__device__ __forceinline__ f16x4 relu_cvt(f32x4 c) {
    return f16x4{(_Float16)fmaxf(c[0],0.f), (_Float16)fmaxf(c[1],0.f),
                 (_Float16)fmaxf(c[2],0.f), (_Float16)fmaxf(c[3],0.f)};
}

__device__ __forceinline__ float pack_f16x2(float a, float b) {
    f16x2 h{(_Float16)a, (_Float16)b};
    return __builtin_bit_cast(float, h);
}

// ---- repack: weights -> K=16 MFMA A-fragment order in d_ws ----
// 32 f16x4 frags (8B/lane): f 0..7 L1 (kc*4+mt, kc<2), 8..23 L2 (kc*4+mt,
// kc<4), 24..31 L3 (kc*2+mt, kc<4). elem j: W'[k=kc*16+quad*4+j][mt*16+col].
// W1 ROW-PERMUTED: k 0..15 = rbf centers (orig rows 2..17), k16=f0(row0),
// k17=f1(row1), k18=b1, k>=19 zero.
// Compact bias table at +16KB: float[128] = {b2[64], b3[32], W4[32]}.
__global__ __launch_bounds__(64) void repack_kernel(
    const float* __restrict__ W1, const float* __restrict__ b1,
    const float* __restrict__ W2, const float* __restrict__ b2,
    const float* __restrict__ W3, const float* __restrict__ b3,
    const float* __restrict__ W4, char* __restrict__ ws)
{
    const int b = blockIdx.x, l = threadIdx.x;
    const int col = l & 15, quad = l >> 4;
    if (b < 32) {
        f16x4 v;
        #pragma unroll
        for (int j = 0; j < 4; ++j) {
            float x;
            if (b < 8) {
                const int kc = b >> 2, mt = b & 3;
                const int k = kc*16 + quad*4 + j;
                if (k < 16)       x = W1[(k+2)*64 + mt*16 + col];  // rbf rows
                else if (k == 16) x = W1[        mt*16 + col];     // f0
                else if (k == 17) x = W1[ 64   + mt*16 + col];     // f1
                else if (k == 18) x = b1[        mt*16 + col];     // bias slot
                else              x = 0.0f;
            } else if (b < 24) {
                const int idx = b - 8, kc = idx >> 2, mt = idx & 3;
                const int k = kc*16 + quad*4 + j;
                x = W2[k*64 + mt*16 + col];
            } else {
                const int idx = b - 24, kc = idx >> 1, mt = idx & 1;
                const int k = kc*16 + quad*4 + j;
                x = W3[k*32 + mt*16 + col];
            }
            v[j] = (_Float16)x;
        }
        *(f16x4*)(ws + (b*64 + l)*8) = v;
    } else {
        float* bo = (float*)(ws + 16384);
        #pragma unroll
        for (int i = l; i < 128; i += 64) {
            float x;
            if (i < 64)       x = b2[i];
            else if (i < 96)  x = b3[i - 64];
            else              x = W4[i - 96];
            bo[i] = x;
        }
    }
}

__global__ __launch_bounds__(256, 4) void aqfn_kernel(
    const float* __restrict__ atom_pos,   // (512,3)
    const float* __restrict__ atom_feat,  // (512,2)
    const float* __restrict__ query_pos,  // (4096,3)
    const float* __restrict__ b4,         // (1)
    const float* __restrict__ W5, const float* __restrict__ b5,  // (3,64),(64)
    const float* __restrict__ W6, const float* __restrict__ b6,  // (64,3),(3)
    const char*  __restrict__ ws,         // repacked weights + compact biases
    float* __restrict__ out)              // (4096,3)
{
    __shared__ __align__(16) float4 rbufs[4][CAP];  // 22528B: per-wave lists
    __shared__ __align__(16) f16x4  wlds[2048];     // 16384B: 32 frags x 64
    __shared__ __align__(16) float  biaslds[128];   //   512B: b2|b3|W4 compact

    const int tid  = threadIdx.x;
    const int wave = __builtin_amdgcn_readfirstlane(tid >> 6);
    const int lane = tid & 63;
    const int col  = lane & 15;
    const int quad = lane >> 4;
    const int q    = blockIdx.x * 4 + wave;   // grid=1024 -> q < 4096 always

    float4* rb = rbufs[wave];

    // ---- stage weights + biases to LDS (coalesced), one barrier below ----
    {
        const f16x4* wsrc = (const f16x4*)ws;
        #pragma unroll
        for (int i = 0; i < 8; ++i)
            wlds[tid + i*256] = wsrc[tid + i*256];
        if (tid < 128) biaslds[tid] = ((const float*)(ws + 16384))[tid];
    }

    const float b4v = b4[0];   // uniform -> SGPR

    const float qx = query_pos[q*3+0];
    const float qy = query_pos[q*3+1];
    const float qz = query_pos[q*3+2];

    // ---- fused compaction: ballot + running prefix, same-wave only ----
    int off = 0;
    #pragma unroll
    for (int it = 0; it < 8; ++it) {
        const int a = it*64 + lane;
        const float rx = qx - atom_pos[a*3+0];
        const float ry = qy - atom_pos[a*3+1];
        const float rz = qz - atom_pos[a*3+2];
        const float f0 = atom_feat[a*2+0];
        const float f1 = atom_feat[a*2+1];
        const float ex = __fadd_rn(rx, 1e-12f);
        const float ey = __fadd_rn(ry, 1e-12f);
        const float ez = __fadd_rn(rz, 1e-12f);
        const float dd = __fadd_rn(__fadd_rn(__fmul_rn(ex,ex), __fmul_rn(ey,ey)),
                                   __fmul_rn(ez,ez));
        const float dist = sqrtf(dd);
        const unsigned long long m = __ballot(dist <= 6.0f);
        const int p = off + (int)__popcll(m & ((1ull << lane) - 1ull));
        if (((m >> lane) & 1ull) && p < CAP)
            rb[p] = make_float4(rx, ry, rz, pack_f16x2(f0, f1));
        off += (int)__popcll(m);
    }
    const int count = off > CAP ? CAP : off;

    // one barrier: wlds/biaslds visible to all waves (rb is same-wave)
    __syncthreads();

    // ---- MLP over this wave's list: 32-pair chunks, weights from LDS ----
    // centers linspace(0,6,16): c_m = 0.4*m. exp(-10 t^2) = 2^(-(s*t)^2),
    // s = sqrt(10*log2 e) = 3.7982831, step 0.4*s = 1.5193132.
    float wacc0 = 0.f, wacc1 = 0.f, wacc2 = 0.f;
    const int nchunks = (count + (NT*16 - 1)) / (NT*16);
    const float cbase = 1.5193132f * (float)(quad*4);

    #pragma unroll 1
    for (int chunk = 0; chunk < nchunks; ++chunk) {
        const int row0 = chunk * (NT*16);

        // opaque zero: all LDS weight/bias addresses depend on it -> the
        // ds_reads can't be LICM'd into resident VGPRs across chunks.
        int wb = 0;
        asm volatile("" : "+v"(wb));
        const float4* bias4 = (const float4*)biaslds;

        float4 rv[NT]; float dvv[NT]; f16x2 ffv[NT];
        #pragma unroll
        for (int u = 0; u < NT; ++u) {
            int pr = row0 + u*16 + col;
            if (pr >= count) pr = count - 1;
            rv[u] = rb[pr];
        }
        #pragma unroll
        for (int u = 0; u < NT; ++u) {
            ffv[u] = __builtin_bit_cast(f16x2, rv[u].w);
            // EXACT pass-1 sequence -> bitwise-identical dist
            const float ex = __fadd_rn(rv[u].x, 1e-12f);
            const float ey = __fadd_rn(rv[u].y, 1e-12f);
            const float ez = __fadd_rn(rv[u].z, 1e-12f);
            const float dd = __fadd_rn(__fadd_rn(__fmul_rn(ex,ex), __fmul_rn(ey,ey)),
                                       __fmul_rn(ez,ez));
            dvv[u] = sqrtf(dd);
        }

        // X B-frags: kc=0 pure RBF (center = quad*4+j), kc=1 = {f0,f1,1,0}|quad0
        f16x4 xa0[NT], xa1[NT];
        #pragma unroll
        for (int u = 0; u < NT; ++u) {
            const float base = __fmul_rn(dvv[u], 3.7982831f) - cbase;
            #pragma unroll
            for (int j = 0; j < 4; ++j) {
                const float t = base - 1.5193132f * (float)j;
                xa0[u][j] = (_Float16)exp2_fast(t * -t);
            }
            const bool q0 = (quad == 0);
            xa1[u] = f16x4{q0 ? ffv[u][0] : (_Float16)0.f,
                           q0 ? ffv[u][1] : (_Float16)0.f,
                           (_Float16)(q0 ? 1.f : 0.f),
                           (_Float16)0.f};
        }

        // ---- L1: transient frag loads; rows mt*16+quad*4+rr -> B-frag kc=mt
        f16x4 t1[2][4];
        #pragma unroll
        for (int kc = 0; kc < 2; ++kc)
            #pragma unroll
            for (int mt = 0; mt < 4; ++mt)
                t1[kc][mt] = wlds[wb + (kc*4 + mt)*64 + lane];
        f16x4 a2[NT][4];
        #pragma unroll
        for (int u = 0; u < NT; ++u)
            #pragma unroll
            for (int mt = 0; mt < 4; ++mt) {
                f32x4 c = {0.f, 0.f, 0.f, 0.f};
                c = MFMA16(t1[0][mt], xa0[u], c);
                c = MFMA16(t1[1][mt], xa1[u], c);
                a2[u][mt] = relu_cvt(c);
            }

        // ---- L2 ----
        f16x4 t2[4][4];
        #pragma unroll
        for (int kc = 0; kc < 4; ++kc)
            #pragma unroll
            for (int mt = 0; mt < 4; ++mt)
                t2[kc][mt] = wlds[wb + (8 + kc*4 + mt)*64 + lane];
        float4 b2v[4];
        #pragma unroll
        for (int mt = 0; mt < 4; ++mt) b2v[mt] = bias4[wb + mt*4 + quad];
        f16x4 a3[NT][4];
        #pragma unroll
        for (int u = 0; u < NT; ++u)
            #pragma unroll
            for (int mt = 0; mt < 4; ++mt) {
                f32x4 c = {b2v[mt].x, b2v[mt].y, b2v[mt].z, b2v[mt].w};
                #pragma unroll
                for (int kc = 0; kc < 4; ++kc)
                    c = MFMA16(t2[kc][mt], a2[u][kc], c);
                a3[u][mt] = relu_cvt(c);
            }

        // ---- L3 + L4 partial + quad-reduce + fused accumulation ----
        f16x4 t3[4][2];
        #pragma unroll
        for (int kc = 0; kc < 4; ++kc)
            #pragma unroll
            for (int mt = 0; mt < 2; ++mt)
                t3[kc][mt] = wlds[wb + (24 + kc*2 + mt)*64 + lane];
        float4 b3v[2], w4v[2];
        #pragma unroll
        for (int mt = 0; mt < 2; ++mt) {
            b3v[mt] = bias4[wb + 16 + mt*4 + quad];
            w4v[mt] = bias4[wb + 24 + mt*4 + quad];
        }
        #pragma unroll
        for (int u = 0; u < NT; ++u) {
            float s = 0.f;
            #pragma unroll
            for (int mt = 0; mt < 2; ++mt) {
                f32x4 c = {b3v[mt].x, b3v[mt].y, b3v[mt].z, b3v[mt].w};
                #pragma unroll
                for (int kc = 0; kc < 4; ++kc)
                    c = MFMA16(t3[kc][mt], a3[u][kc], c);
                const float* wv = &w4v[mt].x;
                #pragma unroll
                for (int rr = 0; rr < 4; ++rr)
                    s = fmaf(fmaxf(c[rr], 0.f), wv[rr], s);
            }
            s += __shfl_xor(s, 16);   // sum quad partials (rows split over quads)
            s += __shfl_xor(s, 32);
            s += b4v;
            const int   p2  = row0 + u*16 + col;
            const float inv = __builtin_amdgcn_rcpf(dvv[u] + 1e-12f);
            const float wm  = (p2 < count) ? (s * inv) : 0.f;
            wacc0 = fmaf(wm, rv[u].x, wacc0);
            wacc1 = fmaf(wm, rv[u].y, wacc1);
            wacc2 = fmaf(wm, rv[u].z, wacc2);
        }
    }

    // ---- 64-lane butterfly; each pair counted by 4 quads -> x0.25 ----
    #pragma unroll
    for (int o = 1; o < 64; o <<= 1) {
        wacc0 += __shfl_xor(wacc0, o);
        wacc1 += __shfl_xor(wacc1, o);
        wacc2 += __shfl_xor(wacc2, o);
    }
    const float v0 = wacc0 * 0.25f;
    const float v1 = wacc1 * 0.25f;
    const float v2 = wacc2 * 0.25f;

    // ---- head: 3 -> 64 -> 3, per wave (lane = hidden unit) ----
    // opaque index: keeps these global loads AFTER the loop (not hoisted into
    // 7 resident VGPRs for the whole kernel)
    int hz = 0;
    asm volatile("" : "+v"(hz));
    const float w5x = W5[hz + lane];
    const float w5y = W5[hz + 64 + lane];
    const float w5z = W5[hz + 128 + lane];
    const float b5v = b5[hz + lane];
    float th = fmaf(v0, w5x, fmaf(v1, w5y, fmaf(v2, w5z, b5v)));
    th = fmaxf(th, 0.f);
    float o0 = th * W6[hz + lane*3+0];
    float o1 = th * W6[hz + lane*3+1];
    float o2 = th * W6[hz + lane*3+2];
    #pragma unroll
    for (int o = 1; o < 64; o <<= 1) {
        o0 += __shfl_xor(o0, o);
        o1 += __shfl_xor(o1, o);
        o2 += __shfl_xor(o2, o);
    }
    if (lane == 0) {
        out[q*3+0] = o0 + b6[0];
        out[q*3+1] = o1 + b6[1];
        out[q*3+2] = o2 + b6[2];
    }
}

extern "C" void kernel_launch(void* const* d_in, const int* in_sizes, int n_in,
                              void* d_out, int out_size, void* d_ws, size_t ws_size,
                              hipStream_t stream) {
    const float* atom_pos  = (const float*)d_in[0];
    const float* atom_feat = (const float*)d_in[1];
    const float* query_pos = (const float*)d_in[2];
    const float* W1 = (const float*)d_in[3];  const float* b1 = (const float*)d_in[4];
    const float* W2 = (const float*)d_in[5];  const float* b2 = (const float*)d_in[6];
    const float* W3 = (const float*)d_in[7];  const float* b3 = (const float*)d_in[8];
    const float* W4 = (const float*)d_in[9];  const float* b4 = (const float*)d_in[10];
    const float* W5 = (const float*)d_in[11]; const float* b5 = (const float*)d_in[12];
    const float* W6 = (const float*)d_in[13]; const float* b6 = (const float*)d_in[14];
    float* out = (float*)d_out;
    char*  ws  = (char*)d_ws;   // 16KB frags + 512B compact biases

    hipLaunchKernelGGL(repack_kernel, dim3(33), dim3(64), 0, stream,
                       W1, b1, W2, b2, W3, b3, W4, ws);
    hipLaunchKernelGGL(aqfn_kernel, dim3(1024), dim3(256), 0, stream,
                       atom_pos, atom_feat, query_pos, b4, W5, b5, W6, b6,
                       (const char*)ws, out);
}

// Round 4
// 100.875 us; speedup vs baseline: 1.2338x; 1.1134x over previous
//
#include <hip/hip_runtime.h>
#include <math.h>

// AtomQueryFieldNet: NQ=4096, NA=512, pair MLP 18->64->64->32->1, cutoff mask,
// per-query 3-vector reduction, 3->64->3 head.
//
// R18: ALGORITHMIC COLLAPSE — per-atom distance table.
//  - Key identity: pair scalar s(q,a) = MLP(f0_a, f1_a, rbf(dist)) depends
//    only on (atom, dist). Tabulate G_a(d) on 512 samples over [0,6] per atom
//    (tabgen_kernel, same f16-MFMA pipeline as R17 -> same base error), then
//    the field kernel is dist + 2-point lerp + s/dist + 3 fmaf per pair.
//  - Work: tabgen 262K MLP evals (~35% of the old 740K per-pair evals);
//    field kernel ~24 VALU ops/pair dense over all 512 atoms — NO compaction,
//    NO per-wave imbalance (uniform 8 iters/wave). R17 spent ~18us VALU +
//    ~7us MFMA on per-pair MLP; that floor is gone.
//  - Interp error: h=6/511, |G''|~2*gamma -> max ~3e-4/pair, RMS over ~180
//    in-range atoms ~3e-3 << passing 0.0156 budget. Table f32; stores s incl
//    b4 (mask & 1/dist applied at runtime, so no 1/d blowup in the table).
//  - dist in field kernel = bitwise-identical __fadd_rn/__fmul_rn/sqrtf
//    sequence as before -> mask boundary identical to all passing rounds.
//  - ws layout: [0,16K) W frags, [16K,16.5K) biases, [32K, 32K+1M) table.
//  - 3 dispatches: repack (unchanged from R17) -> tabgen -> field.

typedef _Float16 f16x4 __attribute__((ext_vector_type(4)));
typedef _Float16 f16x2 __attribute__((ext_vector_type(2)));
typedef float    f32x4 __attribute__((ext_vector_type(4)));

#define NT 2          // 16-sample tiles per tabgen chunk (32 samples/chunk)
#define NS 512        // distance samples per atom over [0,6]

#define MFMA16(A,B,C) __builtin_amdgcn_mfma_f32_16x16x16f16(A,B,C,0,0,0)

__device__ __forceinline__ float exp2_fast(float x) {
    float r;
    asm("v_exp_f32 %0, %1" : "=v"(r) : "v"(x));
    return r;
}

__device__ __forceinline__ f16x4 relu_cvt(f32x4 c) {
    return f16x4{(_Float16)fmaxf(c[0],0.f), (_Float16)fmaxf(c[1],0.f),
                 (_Float16)fmaxf(c[2],0.f), (_Float16)fmaxf(c[3],0.f)};
}

// ---- repack: weights -> K=16 MFMA A-fragment order in d_ws (as R17) ----
// 32 f16x4 frags (8B/lane): f 0..7 L1 (kc*4+mt, kc<2), 8..23 L2 (kc*4+mt,
// kc<4), 24..31 L3 (kc*2+mt, kc<4). elem j: W'[k=kc*16+quad*4+j][mt*16+col].
// W1 ROW-PERMUTED: k 0..15 = rbf centers (orig rows 2..17), k16=f0(row0),
// k17=f1(row1), k18=b1, k>=19 zero.
// Compact bias table at +16KB: float[128] = {b2[64], b3[32], W4[32]}.
__global__ __launch_bounds__(64) void repack_kernel(
    const float* __restrict__ W1, const float* __restrict__ b1,
    const float* __restrict__ W2, const float* __restrict__ b2,
    const float* __restrict__ W3, const float* __restrict__ b3,
    const float* __restrict__ W4, char* __restrict__ ws)
{
    const int b = blockIdx.x, l = threadIdx.x;
    const int col = l & 15, quad = l >> 4;
    if (b < 32) {
        f16x4 v;
        #pragma unroll
        for (int j = 0; j < 4; ++j) {
            float x;
            if (b < 8) {
                const int kc = b >> 2, mt = b & 3;
                const int k = kc*16 + quad*4 + j;
                if (k < 16)       x = W1[(k+2)*64 + mt*16 + col];  // rbf rows
                else if (k == 16) x = W1[        mt*16 + col];     // f0
                else if (k == 17) x = W1[ 64   + mt*16 + col];     // f1
                else if (k == 18) x = b1[        mt*16 + col];     // bias slot
                else              x = 0.0f;
            } else if (b < 24) {
                const int idx = b - 8, kc = idx >> 2, mt = idx & 3;
                const int k = kc*16 + quad*4 + j;
                x = W2[k*64 + mt*16 + col];
            } else {
                const int idx = b - 24, kc = idx >> 1, mt = idx & 1;
                const int k = kc*16 + quad*4 + j;
                x = W3[k*32 + mt*16 + col];
            }
            v[j] = (_Float16)x;
        }
        *(f16x4*)(ws + (b*64 + l)*8) = v;
    } else {
        float* bo = (float*)(ws + 16384);
        #pragma unroll
        for (int i = l; i < 128; i += 64) {
            float x;
            if (i < 64)       x = b2[i];
            else if (i < 96)  x = b3[i - 64];
            else              x = W4[i - 96];
            bo[i] = x;
        }
    }
}

// ---- tabgen: G_a(d_i) for a in [0,512), i in [0,NS), d_i = i*6/(NS-1) ----
// One 32-sample chunk per wave; chunks/atom = NS/32 = 16; grid = 2048 blocks.
// MLP body identical to R17's verified chunk loop (xa0 RBF, xa1={f0,f1,1,0}).
// Stores raw s (incl b4); mask and 1/dist applied by field kernel.
__global__ __launch_bounds__(256, 4) void tabgen_kernel(
    const float* __restrict__ atom_feat,  // (512,2)
    const float* __restrict__ b4,         // (1)
    const char*  __restrict__ ws,         // repacked weights + biases
    float* __restrict__ tab)              // (512, NS)
{
    __shared__ __align__(16) f16x4 wlds[2048];     // 16KB frags
    __shared__ __align__(16) float biaslds[128];   // 512B biases

    const int tid  = threadIdx.x;
    const int wave = __builtin_amdgcn_readfirstlane(tid >> 6);
    const int lane = tid & 63;
    const int col  = lane & 15;
    const int quad = lane >> 4;

    {
        const f16x4* wsrc = (const f16x4*)ws;
        #pragma unroll
        for (int i = 0; i < 8; ++i)
            wlds[tid + i*256] = wsrc[tid + i*256];
        if (tid < 128) biaslds[tid] = ((const float*)(ws + 16384))[tid];
    }
    __syncthreads();

    const int c  = blockIdx.x * 4 + wave;   // 0..8191
    const int a  = c >> 4;                  // atom (16 chunks per atom)
    const int i0 = (c & 15) * 32;           // sample base
    const float f0 = atom_feat[a*2+0];      // wave-uniform -> scalar
    const float f1 = atom_feat[a*2+1];
    const float b4v = b4[0];
    const float4* bias4 = (const float4*)biaslds;

    // centers linspace(0,6,16): exp(-10 t^2) = 2^(-(s*t)^2),
    // s = sqrt(10*log2 e) = 3.7982831, step 0.4*s = 1.5193132.
    const float cbase = 1.5193132f * (float)(quad*4);

    f16x4 xa0[NT], xa1[NT];
    #pragma unroll
    for (int u = 0; u < NT; ++u) {
        const int   idx  = i0 + u*16 + col;
        const float dist = (float)idx * (6.0f/511.0f);
        const float base = __fmul_rn(dist, 3.7982831f) - cbase;
        #pragma unroll
        for (int j = 0; j < 4; ++j) {
            const float t = base - 1.5193132f * (float)j;
            xa0[u][j] = (_Float16)exp2_fast(t * -t);
        }
        const bool q0 = (quad == 0);
        xa1[u] = f16x4{q0 ? (_Float16)f0 : (_Float16)0.f,
                       q0 ? (_Float16)f1 : (_Float16)0.f,
                       (_Float16)(q0 ? 1.f : 0.f),
                       (_Float16)0.f};
    }

    // ---- L1 ----
    f16x4 t1[2][4];
    #pragma unroll
    for (int kc = 0; kc < 2; ++kc)
        #pragma unroll
        for (int mt = 0; mt < 4; ++mt)
            t1[kc][mt] = wlds[(kc*4 + mt)*64 + lane];
    f16x4 a2[NT][4];
    #pragma unroll
    for (int u = 0; u < NT; ++u)
        #pragma unroll
        for (int mt = 0; mt < 4; ++mt) {
            f32x4 cc = {0.f, 0.f, 0.f, 0.f};
            cc = MFMA16(t1[0][mt], xa0[u], cc);
            cc = MFMA16(t1[1][mt], xa1[u], cc);
            a2[u][mt] = relu_cvt(cc);
        }

    // ---- L2 ----
    f16x4 t2[4][4];
    #pragma unroll
    for (int kc = 0; kc < 4; ++kc)
        #pragma unroll
        for (int mt = 0; mt < 4; ++mt)
            t2[kc][mt] = wlds[(8 + kc*4 + mt)*64 + lane];
    float4 b2v[4];
    #pragma unroll
    for (int mt = 0; mt < 4; ++mt) b2v[mt] = bias4[mt*4 + quad];
    f16x4 a3[NT][4];
    #pragma unroll
    for (int u = 0; u < NT; ++u)
        #pragma unroll
        for (int mt = 0; mt < 4; ++mt) {
            f32x4 cc = {b2v[mt].x, b2v[mt].y, b2v[mt].z, b2v[mt].w};
            #pragma unroll
            for (int kc = 0; kc < 4; ++kc)
                cc = MFMA16(t2[kc][mt], a2[u][kc], cc);
            a3[u][mt] = relu_cvt(cc);
        }

    // ---- L3 + L4 partial + quad-reduce -> store ----
    f16x4 t3[4][2];
    #pragma unroll
    for (int kc = 0; kc < 4; ++kc)
        #pragma unroll
        for (int mt = 0; mt < 2; ++mt)
            t3[kc][mt] = wlds[(24 + kc*2 + mt)*64 + lane];
    float4 b3v[2], w4v[2];
    #pragma unroll
    for (int mt = 0; mt < 2; ++mt) {
        b3v[mt] = bias4[16 + mt*4 + quad];
        w4v[mt] = bias4[24 + mt*4 + quad];
    }
    #pragma unroll
    for (int u = 0; u < NT; ++u) {
        float s = 0.f;
        #pragma unroll
        for (int mt = 0; mt < 2; ++mt) {
            f32x4 cc = {b3v[mt].x, b3v[mt].y, b3v[mt].z, b3v[mt].w};
            #pragma unroll
            for (int kc = 0; kc < 4; ++kc)
                cc = MFMA16(t3[kc][mt], a3[u][kc], cc);
            const float* wv = &w4v[mt].x;
            #pragma unroll
            for (int rr = 0; rr < 4; ++rr)
                s = fmaf(fmaxf(cc[rr], 0.f), wv[rr], s);
        }
        s += __shfl_xor(s, 16);   // sum quad partials (rows split over quads)
        s += __shfl_xor(s, 32);
        s += b4v;
        if (quad == 0)
            tab[a*NS + i0 + u*16 + col] = s;   // 64B store per 16-lane group
    }
}

// ---- field: dense 512-atom sweep, table lookup + lerp, head ----
__global__ __launch_bounds__(256, 4) void field_kernel(
    const float* __restrict__ atom_pos,   // (512,3)
    const float* __restrict__ query_pos,  // (4096,3)
    const float* __restrict__ W5, const float* __restrict__ b5,  // (3,64),(64)
    const float* __restrict__ W6, const float* __restrict__ b6,  // (64,3),(3)
    const float* __restrict__ tab,        // (512, NS)
    float* __restrict__ out)              // (4096,3)
{
    __shared__ float px[512], py[512], pz[512];   // 6KB SoA, conflict-free

    const int tid  = threadIdx.x;
    const int wave = __builtin_amdgcn_readfirstlane(tid >> 6);
    const int lane = tid & 63;
    const int q    = blockIdx.x * 4 + wave;   // grid=1024 -> q < 4096

    #pragma unroll
    for (int i = tid; i < 512; i += 256) {
        px[i] = atom_pos[i*3+0];
        py[i] = atom_pos[i*3+1];
        pz[i] = atom_pos[i*3+2];
    }
    __syncthreads();

    const float qx = query_pos[q*3+0];
    const float qy = query_pos[q*3+1];
    const float qz = query_pos[q*3+2];

    float acc0 = 0.f, acc1 = 0.f, acc2 = 0.f;
    #pragma unroll
    for (int it = 0; it < 8; ++it) {
        const int a = it*64 + lane;
        const float rx = qx - px[a];
        const float ry = qy - py[a];
        const float rz = qz - pz[a];
        // EXACT reference dist sequence (mask boundary bitwise-stable)
        const float ex = __fadd_rn(rx, 1e-12f);
        const float ey = __fadd_rn(ry, 1e-12f);
        const float ez = __fadd_rn(rz, 1e-12f);
        const float dd = __fadd_rn(__fadd_rn(__fmul_rn(ex,ex), __fmul_rn(ey,ey)),
                                   __fmul_rn(ez,ez));
        const float dist = sqrtf(dd);
        const bool  in   = dist <= 6.0f;
        // table lookup: t in [0,511] for in-range; clamp keeps OOR lanes
        // in-row (their result is masked anyway)
        const float t  = __fmul_rn(dist, 85.166664f);   // (NS-1)/6
        int   i  = (int)t;
        i = i < (NS-2) ? i : (NS-2);
        const float frac = t - (float)i;
        const float* row = tab + a*NS;
        const float s0 = row[i];
        const float s1 = row[i+1];
        const float sv = fmaf(frac, s1 - s0, s0);
        const float inv = __builtin_amdgcn_rcpf(dist + 1e-12f);
        const float wm  = in ? sv * inv : 0.f;
        acc0 = fmaf(wm, rx, acc0);
        acc1 = fmaf(wm, ry, acc1);
        acc2 = fmaf(wm, rz, acc2);
    }

    // ---- 64-lane butterfly (each atom counted exactly once) ----
    #pragma unroll
    for (int o = 1; o < 64; o <<= 1) {
        acc0 += __shfl_xor(acc0, o);
        acc1 += __shfl_xor(acc1, o);
        acc2 += __shfl_xor(acc2, o);
    }

    // ---- head: 3 -> 64 -> 3, per wave (lane = hidden unit) ----
    int hz = 0;
    asm volatile("" : "+v"(hz));   // keep head loads after the loop
    const float w5x = W5[hz + lane];
    const float w5y = W5[hz + 64 + lane];
    const float w5z = W5[hz + 128 + lane];
    const float b5v = b5[hz + lane];
    float th = fmaf(acc0, w5x, fmaf(acc1, w5y, fmaf(acc2, w5z, b5v)));
    th = fmaxf(th, 0.f);
    float o0 = th * W6[hz + lane*3+0];
    float o1 = th * W6[hz + lane*3+1];
    float o2 = th * W6[hz + lane*3+2];
    #pragma unroll
    for (int o = 1; o < 64; o <<= 1) {
        o0 += __shfl_xor(o0, o);
        o1 += __shfl_xor(o1, o);
        o2 += __shfl_xor(o2, o);
    }
    if (lane == 0) {
        out[q*3+0] = o0 + b6[0];
        out[q*3+1] = o1 + b6[1];
        out[q*3+2] = o2 + b6[2];
    }
}

extern "C" void kernel_launch(void* const* d_in, const int* in_sizes, int n_in,
                              void* d_out, int out_size, void* d_ws, size_t ws_size,
                              hipStream_t stream) {
    const float* atom_pos  = (const float*)d_in[0];
    const float* atom_feat = (const float*)d_in[1];
    const float* query_pos = (const float*)d_in[2];
    const float* W1 = (const float*)d_in[3];  const float* b1 = (const float*)d_in[4];
    const float* W2 = (const float*)d_in[5];  const float* b2 = (const float*)d_in[6];
    const float* W3 = (const float*)d_in[7];  const float* b3 = (const float*)d_in[8];
    const float* W4 = (const float*)d_in[9];  const float* b4 = (const float*)d_in[10];
    const float* W5 = (const float*)d_in[11]; const float* b5 = (const float*)d_in[12];
    const float* W6 = (const float*)d_in[13]; const float* b6 = (const float*)d_in[14];
    float* out = (float*)d_out;
    char*  ws  = (char*)d_ws;
    float* tab = (float*)(ws + 32768);   // 512*NS*4 = 1MB table

    hipLaunchKernelGGL(repack_kernel, dim3(33), dim3(64), 0, stream,
                       W1, b1, W2, b2, W3, b3, W4, ws);
    hipLaunchKernelGGL(tabgen_kernel, dim3(2048), dim3(256), 0, stream,
                       atom_feat, b4, (const char*)ws, tab);
    hipLaunchKernelGGL(field_kernel, dim3(1024), dim3(256), 0, stream,
                       atom_pos, query_pos, W5, b5, W6, b6,
                       (const float*)tab, out);
}

// Round 5
// 100.350 us; speedup vs baseline: 1.2402x; 1.0052x over previous
//
#include <hip/hip_runtime.h>
#include <math.h>

// AtomQueryFieldNet: NQ=4096, NA=512, pair MLP 18->64->64->32->1, cutoff mask,
// per-query 3-vector reduction, 3->64->3 head.
//
// R19: 2 dispatches, bit-identical to R18's math.
//  - R18 (22us kernel path): repack + tabgen(2048 blocks, 2 rounds) + field.
//    repack is pure launch overhead; tabgen re-staged 16KB weights x2048
//    blocks (32MB L2) across 2 scheduling rounds.
//  - R19: repack FUSED into tabgen — each block gathers W1..W4/biases from
//    global straight into LDS (same f32->f16 cvt chain -> same wlds bits ->
//    same table bits -> same output bits). Tabgen grid 1024 = one full
//    4-blocks/CU round; each wave does 2 consecutive 32-sample chunks
//    (provably same atom: 16 chunks/atom, even alignment) -> f0/f1 hoisted
//    wave-uniform, staging halved to 16MB.
//  - Chunk loop: #pragma unroll 1 + opaque wb offset -> frag ds_reads stay
//    transient (no 64-VGPR resident weight blow-up under (256,4)).
//  - Table identity (R18): pair scalar s(q,a)=MLP(f0_a,f1_a,rbf(d)) depends
//    only on (atom,d) -> tabulate G_a(d), NS=512 over [0,6]; field kernel =
//    dist + 2-pt lerp + s/d + 3 fmaf per pair, dense over 512 atoms, no
//    compaction. dist uses the EXACT reference __fadd_rn/__fmul_rn/sqrtf
//    sequence -> cutoff boundary bitwise-stable. absmax 0.015625 (f16 floor).
//  - ws layout: [0, 1MB) table only.

typedef _Float16 f16x4 __attribute__((ext_vector_type(4)));
typedef _Float16 f16x2 __attribute__((ext_vector_type(2)));
typedef float    f32x4 __attribute__((ext_vector_type(4)));

#define NS 512        // distance samples per atom over [0,6]

#define MFMA16(A,B,C) __builtin_amdgcn_mfma_f32_16x16x16f16(A,B,C,0,0,0)

__device__ __forceinline__ float exp2_fast(float x) {
    float r;
    asm("v_exp_f32 %0, %1" : "=v"(r) : "v"(x));
    return r;
}

__device__ __forceinline__ f16x4 relu_cvt(f32x4 c) {
    return f16x4{(_Float16)fmaxf(c[0],0.f), (_Float16)fmaxf(c[1],0.f),
                 (_Float16)fmaxf(c[2],0.f), (_Float16)fmaxf(c[3],0.f)};
}

// ---- tabgen: G_a(d_i), a in [0,512), i in [0,NS), d_i = i*6/511 ----
// Fused in-block repack: wlds frag layout (32 f16x4 frags x 64 lanes):
//   f 0..7  L1 (kc*4+mt, kc<2)   elem j: W1'[k=kc*16+quad*4+j][mt*16+col]
//   f 8..23 L2 (kc*4+mt, kc<4)           W2 [k][mt*16+col]
//   f 24..31 L3 (kc*2+mt, kc<4)          W3 [k][mt*16+col]
// W1' ROW-PERMUTED: k 0..15 = rbf rows (orig 2..17), k16=f0(row0),
// k17=f1(row1), k18=b1, k>=19 zero. biaslds[128] = {b2[64], b3[32], W4[32]}.
// Grid 1024 x 256: wave wc = bid*4+wave owns atom wc>>3, samples
// [(wc&7)*64, +64) as 2 chunks of 32.
__global__ __launch_bounds__(256, 4) void tabgen_kernel(
    const float* __restrict__ atom_feat,  // (512,2)
    const float* __restrict__ W1, const float* __restrict__ b1,
    const float* __restrict__ W2, const float* __restrict__ b2,
    const float* __restrict__ W3, const float* __restrict__ b3,
    const float* __restrict__ W4, const float* __restrict__ b4,
    float* __restrict__ tab)              // (512, NS)
{
    __shared__ __align__(16) f16x4 wlds[2048];     // 16KB frags
    __shared__ __align__(16) float biaslds[128];   // 512B biases

    const int tid  = threadIdx.x;
    const int wave = __builtin_amdgcn_readfirstlane(tid >> 6);
    const int lane = tid & 63;
    const int col  = lane & 15;
    const int quad = lane >> 4;

    // ---- fused repack: global -> LDS (8 frag slots per thread) ----
    #pragma unroll
    for (int sidx = 0; sidx < 8; ++sidx) {
        const int s  = tid + sidx*256;     // slot = frag*64 + lane
        const int b  = s >> 6;
        const int sl = s & 63;
        const int scol = sl & 15, squad = sl >> 4;
        f16x4 v;
        #pragma unroll
        for (int j = 0; j < 4; ++j) {
            float x;
            if (b < 8) {
                const int kc = b >> 2, mt = b & 3;
                const int k = kc*16 + squad*4 + j;
                if (k < 16)       x = W1[(k+2)*64 + mt*16 + scol];  // rbf rows
                else if (k == 16) x = W1[        mt*16 + scol];     // f0
                else if (k == 17) x = W1[ 64   + mt*16 + scol];     // f1
                else if (k == 18) x = b1[        mt*16 + scol];     // bias slot
                else              x = 0.0f;
            } else if (b < 24) {
                const int idx = b - 8, kc = idx >> 2, mt = idx & 3;
                const int k = kc*16 + squad*4 + j;
                x = W2[k*64 + mt*16 + scol];
            } else {
                const int idx = b - 24, kc = idx >> 1, mt = idx & 1;
                const int k = kc*16 + squad*4 + j;
                x = W3[k*32 + mt*16 + scol];
            }
            v[j] = (_Float16)x;
        }
        wlds[s] = v;
    }
    if (tid < 128) {
        float x;
        if (tid < 64)       x = b2[tid];
        else if (tid < 96)  x = b3[tid - 64];
        else                x = W4[tid - 96];
        biaslds[tid] = x;
    }
    __syncthreads();

    const int wc     = blockIdx.x * 4 + wave;  // 0..4095
    const int a      = wc >> 3;                // atom (8 waves per atom)
    const int i0base = (wc & 7) * 64;          // 64-sample span, 2 chunks
    const float f0  = atom_feat[a*2+0];        // wave-uniform
    const float f1  = atom_feat[a*2+1];
    const float b4v = b4[0];

    // centers linspace(0,6,16): exp(-10 t^2) = 2^(-(s*t)^2),
    // s = sqrt(10*log2 e) = 3.7982831, step 0.4*s = 1.5193132.
    const float cbase = 1.5193132f * (float)(quad*4);

    #pragma unroll 1
    for (int cc = 0; cc < 2; ++cc) {
        const int i0 = i0base + cc*32;

        // opaque zero: keeps frag/bias ds_reads transient per chunk
        int wb = 0;
        asm volatile("" : "+v"(wb));
        const float4* bias4 = (const float4*)biaslds;

        f16x4 xa0[2], xa1[2];
        #pragma unroll
        for (int u = 0; u < 2; ++u) {
            const int   idx  = i0 + u*16 + col;
            const float dist = (float)idx * (6.0f/511.0f);
            const float base = __fmul_rn(dist, 3.7982831f) - cbase;
            #pragma unroll
            for (int j = 0; j < 4; ++j) {
                const float t = base - 1.5193132f * (float)j;
                xa0[u][j] = (_Float16)exp2_fast(t * -t);
            }
            const bool q0 = (quad == 0);
            xa1[u] = f16x4{q0 ? (_Float16)f0 : (_Float16)0.f,
                           q0 ? (_Float16)f1 : (_Float16)0.f,
                           (_Float16)(q0 ? 1.f : 0.f),
                           (_Float16)0.f};
        }

        // ---- L1 ----
        f16x4 t1[2][4];
        #pragma unroll
        for (int kc = 0; kc < 2; ++kc)
            #pragma unroll
            for (int mt = 0; mt < 4; ++mt)
                t1[kc][mt] = wlds[wb + (kc*4 + mt)*64 + lane];
        f16x4 a2[2][4];
        #pragma unroll
        for (int u = 0; u < 2; ++u)
            #pragma unroll
            for (int mt = 0; mt < 4; ++mt) {
                f32x4 cc2 = {0.f, 0.f, 0.f, 0.f};
                cc2 = MFMA16(t1[0][mt], xa0[u], cc2);
                cc2 = MFMA16(t1[1][mt], xa1[u], cc2);
                a2[u][mt] = relu_cvt(cc2);
            }

        // ---- L2 ----
        f16x4 t2[4][4];
        #pragma unroll
        for (int kc = 0; kc < 4; ++kc)
            #pragma unroll
            for (int mt = 0; mt < 4; ++mt)
                t2[kc][mt] = wlds[wb + (8 + kc*4 + mt)*64 + lane];
        float4 b2v[4];
        #pragma unroll
        for (int mt = 0; mt < 4; ++mt) b2v[mt] = bias4[wb + mt*4 + quad];
        f16x4 a3[2][4];
        #pragma unroll
        for (int u = 0; u < 2; ++u)
            #pragma unroll
            for (int mt = 0; mt < 4; ++mt) {
                f32x4 cc2 = {b2v[mt].x, b2v[mt].y, b2v[mt].z, b2v[mt].w};
                #pragma unroll
                for (int kc = 0; kc < 4; ++kc)
                    cc2 = MFMA16(t2[kc][mt], a2[u][kc], cc2);
                a3[u][mt] = relu_cvt(cc2);
            }

        // ---- L3 + L4 partial + quad-reduce -> store ----
        f16x4 t3[4][2];
        #pragma unroll
        for (int kc = 0; kc < 4; ++kc)
            #pragma unroll
            for (int mt = 0; mt < 2; ++mt)
                t3[kc][mt] = wlds[wb + (24 + kc*2 + mt)*64 + lane];
        float4 b3v[2], w4v[2];
        #pragma unroll
        for (int mt = 0; mt < 2; ++mt) {
            b3v[mt] = bias4[wb + 16 + mt*4 + quad];
            w4v[mt] = bias4[wb + 24 + mt*4 + quad];
        }
        #pragma unroll
        for (int u = 0; u < 2; ++u) {
            float s = 0.f;
            #pragma unroll
            for (int mt = 0; mt < 2; ++mt) {
                f32x4 cc2 = {b3v[mt].x, b3v[mt].y, b3v[mt].z, b3v[mt].w};
                #pragma unroll
                for (int kc = 0; kc < 4; ++kc)
                    cc2 = MFMA16(t3[kc][mt], a3[u][kc], cc2);
                const float* wv = &w4v[mt].x;
                #pragma unroll
                for (int rr = 0; rr < 4; ++rr)
                    s = fmaf(fmaxf(cc2[rr], 0.f), wv[rr], s);
            }
            s += __shfl_xor(s, 16);   // sum quad partials
            s += __shfl_xor(s, 32);
            s += b4v;
            if (quad == 0)
                tab[a*NS + i0 + u*16 + col] = s;
        }
    }
}

// ---- field: dense 512-atom sweep, table lookup + lerp, head ----
__global__ __launch_bounds__(256, 4) void field_kernel(
    const float* __restrict__ atom_pos,   // (512,3)
    const float* __restrict__ query_pos,  // (4096,3)
    const float* __restrict__ W5, const float* __restrict__ b5,  // (3,64),(64)
    const float* __restrict__ W6, const float* __restrict__ b6,  // (64,3),(3)
    const float* __restrict__ tab,        // (512, NS)
    float* __restrict__ out)              // (4096,3)
{
    __shared__ float px[512], py[512], pz[512];   // 6KB SoA, conflict-free

    const int tid  = threadIdx.x;
    const int wave = __builtin_amdgcn_readfirstlane(tid >> 6);
    const int lane = tid & 63;
    const int q    = blockIdx.x * 4 + wave;   // grid=1024 -> q < 4096

    #pragma unroll
    for (int i = tid; i < 512; i += 256) {
        px[i] = atom_pos[i*3+0];
        py[i] = atom_pos[i*3+1];
        pz[i] = atom_pos[i*3+2];
    }
    __syncthreads();

    const float qx = query_pos[q*3+0];
    const float qy = query_pos[q*3+1];
    const float qz = query_pos[q*3+2];

    float acc0 = 0.f, acc1 = 0.f, acc2 = 0.f;
    #pragma unroll
    for (int it = 0; it < 8; ++it) {
        const int a = it*64 + lane;
        const float rx = qx - px[a];
        const float ry = qy - py[a];
        const float rz = qz - pz[a];
        // EXACT reference dist sequence (mask boundary bitwise-stable)
        const float ex = __fadd_rn(rx, 1e-12f);
        const float ey = __fadd_rn(ry, 1e-12f);
        const float ez = __fadd_rn(rz, 1e-12f);
        const float dd = __fadd_rn(__fadd_rn(__fmul_rn(ex,ex), __fmul_rn(ey,ey)),
                                   __fmul_rn(ez,ez));
        const float dist = sqrtf(dd);
        const bool  in   = dist <= 6.0f;
        const float t  = __fmul_rn(dist, 85.166664f);   // (NS-1)/6
        int   i  = (int)t;
        i = i < (NS-2) ? i : (NS-2);
        const float frac = t - (float)i;
        const float* row = tab + a*NS;
        const float s0 = row[i];
        const float s1 = row[i+1];
        const float sv = fmaf(frac, s1 - s0, s0);
        const float inv = __builtin_amdgcn_rcpf(dist + 1e-12f);
        const float wm  = in ? sv * inv : 0.f;
        acc0 = fmaf(wm, rx, acc0);
        acc1 = fmaf(wm, ry, acc1);
        acc2 = fmaf(wm, rz, acc2);
    }

    // ---- 64-lane butterfly (each atom counted exactly once) ----
    #pragma unroll
    for (int o = 1; o < 64; o <<= 1) {
        acc0 += __shfl_xor(acc0, o);
        acc1 += __shfl_xor(acc1, o);
        acc2 += __shfl_xor(acc2, o);
    }

    // ---- head: 3 -> 64 -> 3, per wave (lane = hidden unit) ----
    int hz = 0;
    asm volatile("" : "+v"(hz));   // keep head loads after the loop
    const float w5x = W5[hz + lane];
    const float w5y = W5[hz + 64 + lane];
    const float w5z = W5[hz + 128 + lane];
    const float b5v = b5[hz + lane];
    float th = fmaf(acc0, w5x, fmaf(acc1, w5y, fmaf(acc2, w5z, b5v)));
    th = fmaxf(th, 0.f);
    float o0 = th * W6[hz + lane*3+0];
    float o1 = th * W6[hz + lane*3+1];
    float o2 = th * W6[hz + lane*3+2];
    #pragma unroll
    for (int o = 1; o < 64; o <<= 1) {
        o0 += __shfl_xor(o0, o);
        o1 += __shfl_xor(o1, o);
        o2 += __shfl_xor(o2, o);
    }
    if (lane == 0) {
        out[q*3+0] = o0 + b6[0];
        out[q*3+1] = o1 + b6[1];
        out[q*3+2] = o2 + b6[2];
    }
}

extern "C" void kernel_launch(void* const* d_in, const int* in_sizes, int n_in,
                              void* d_out, int out_size, void* d_ws, size_t ws_size,
                              hipStream_t stream) {
    const float* atom_pos  = (const float*)d_in[0];
    const float* atom_feat = (const float*)d_in[1];
    const float* query_pos = (const float*)d_in[2];
    const float* W1 = (const float*)d_in[3];  const float* b1 = (const float*)d_in[4];
    const float* W2 = (const float*)d_in[5];  const float* b2 = (const float*)d_in[6];
    const float* W3 = (const float*)d_in[7];  const float* b3 = (const float*)d_in[8];
    const float* W4 = (const float*)d_in[9];  const float* b4 = (const float*)d_in[10];
    const float* W5 = (const float*)d_in[11]; const float* b5 = (const float*)d_in[12];
    const float* W6 = (const float*)d_in[13]; const float* b6 = (const float*)d_in[14];
    float* out = (float*)d_out;
    float* tab = (float*)d_ws;   // 512*NS*4 = 1MB table

    hipLaunchKernelGGL(tabgen_kernel, dim3(1024), dim3(256), 0, stream,
                       atom_feat, W1, b1, W2, b2, W3, b3, W4, b4, tab);
    hipLaunchKernelGGL(field_kernel, dim3(1024), dim3(256), 0, stream,
                       atom_pos, query_pos, W5, b5, W6, b6,
                       (const float*)tab, out);
}